// Round 1
// baseline (207.173 us; speedup 1.0000x reference)
//
#include <hip/hip_runtime.h>

#define N_IMG 9216
#define DFEAT 1024
#define NBR 72           // 128-row panels
#define NPAIR 1332       // sum over bcol<36 of min(72, 2*bcol+2)
#define MLPB 288         // mlp blocks (32 rows each)
#define NGRID (NPAIR + MLPB)

typedef __attribute__((ext_vector_type(8))) short short8;
typedef __attribute__((ext_vector_type(4))) float floatx4;
typedef __attribute__((ext_vector_type(16))) float floatx16;
typedef __attribute__((ext_vector_type(4))) int intx4;
typedef __attribute__((ext_vector_type(8))) int intx8;

// exp2-folded constants: sim = exp2(delta - gamma * rcp(1+u))
//   delta_ij = Pi*Pj          (P = sqrt(s) * C2, C2 = sqrt(2*log2e/1024))
//   gamma_ij = s~i + s~j + delta_ij   (s~ = s * C1, C1 = log2e/1024)
// fp4 path: Gram g = sum(z_i z_j), z = 32*normalized -> u = g/1024;
// rcp(1+u) = 1024*rcp(1024+g).
#define C1F 0.0014088818759657845f
#define C2F 0.05308355472172724f

__device__ __forceinline__ void async_copy16(const void* g, void* l) {
  __builtin_amdgcn_global_load_lds((const __attribute__((address_space(1))) void*)g,
                                   (__attribute__((address_space(3))) void*)l,
                                   16, 0, 0);
}

__device__ __forceinline__ unsigned short f2bf(float x) {
  union { float f; unsigned u; } a; a.f = x;
  unsigned u = a.u;
  u += 0x7fffu + ((u >> 16) & 1u);   // round-to-nearest-even
  return (unsigned short)(u >> 16);
}

// ---- fp4 e2m1 quantizer (RNE midpoints), values {0,.5,1,1.5,2,3,4,6} ----
__device__ __forceinline__ unsigned q4(float z) {
  unsigned sg = (__float_as_uint(z) >> 28) & 8u;
  float a = fabsf(z);
  unsigned c = (a < 0.25f) ? 0u : (a < 0.75f) ? 1u : (a < 1.25f) ? 2u :
               (a < 1.75f) ? 3u : (a < 2.5f)  ? 4u : (a < 3.5f)  ? 5u :
               (a < 5.0f)  ? 6u : 7u;
  return c | sg;
}
__device__ __forceinline__ unsigned short pk4(float4 v, float sc) {
  unsigned b0 = q4(v.x * sc) | (q4(v.y * sc) << 4);
  unsigned b1 = q4(v.z * sc) | (q4(v.w * sc) << 4);
  return (unsigned short)(b0 | (b1 << 8));
}

__device__ __forceinline__ intx8 ext8(intx4 v) {
  intx8 r;
  r[0] = v[0]; r[1] = v[1]; r[2] = v[2]; r[3] = v[3];
  r[4] = 0; r[5] = 0; r[6] = 0; r[7] = 0;   // fp4 uses low 4 regs only
  return r;
}

// ---- kernel 1: fp32 -> fp4 fragment-tiled + s~/P; also W1^T bf16; init sums ----
// tiled layout: fbT[rt][kb][r32][32B], rt=row>>5 (288 tiles), kb=k>>6 (16),
// r32=row&31; one (rt,kb) slab = 1024 B = one wave's perfectly-coalesced frag.
__global__ __launch_bounds__(256) void convert_prep(const float* __restrict__ f,
                                                    const float* __restrict__ W1,
                                                    unsigned char* __restrict__ fbT,
                                                    float* __restrict__ sL,
                                                    float* __restrict__ pL,
                                                    unsigned short* __restrict__ W1t,
                                                    double* __restrict__ sums,
                                                    unsigned* __restrict__ ctr) {
  int b = blockIdx.x, t = threadIdx.x;
  if (b < 2304) {
    int lane = t & 63, wave = t >> 6;
    int row = b * 4 + wave;                      // one wave per row
    const float4* src = (const float4*)f + (size_t)row * 256;
    float4 v0 = src[lane], v1 = src[64 + lane], v2 = src[128 + lane], v3 = src[192 + lane];
    float s = v0.x * v0.x + v0.y * v0.y + v0.z * v0.z + v0.w * v0.w
            + v1.x * v1.x + v1.y * v1.y + v1.z * v1.z + v1.w * v1.w
            + v2.x * v2.x + v2.y * v2.y + v2.z * v2.z + v2.w * v2.w
            + v3.x * v3.x + v3.y * v3.y + v3.z * v3.z + v3.w * v3.w;
#pragma unroll
    for (int off = 32; off > 0; off >>= 1) s += __shfl_xor(s, off, 64);
    float zsc = rsqrtf(s) * 32.f;                // z ~ N(0,1)
    unsigned short u0 = pk4(v0, zsc), u1 = pk4(v1, zsc),
                   u2 = pk4(v2, zsc), u3 = pk4(v3, zsc);
    // lane holds elems 256j+4*lane..+3 -> kb_j = 4j + (lane>>4), byte 2*(lane&15)
    unsigned char* tb = fbT + (size_t)(row >> 5) * 16384 + (row & 31) * 32 + (lane & 15) * 2;
    int ko = (lane >> 4) * 1024;
    *(unsigned short*)(tb + ko) = u0;
    *(unsigned short*)(tb + ko + 4096) = u1;
    *(unsigned short*)(tb + ko + 8192) = u2;
    *(unsigned short*)(tb + ko + 12288) = u3;
    if (lane == 0) {
      sL[row] = s * C1F;
      pL[row] = sqrtf(s) * C2F;
    }
  } else {
    int j = b - 2304;                            // W1 column j -> W1t row j
    if (j == 0) {
      if (t < 2) sums[t] = 0.0;
      if (t == 2) *ctr = 0u;                     // completion counter for fused
    }
    for (int k = t; k < DFEAT; k += 256)
      W1t[(size_t)j * DFEAT + k] = f2bf(W1[(size_t)k * 128 + j]);
  }
}

// ---- kernel 2 (fused): Gram+sim (blocks >= MLPB), full MLP (blocks < MLPB),
//      and finalize (last block via device-scope completion counter).
// mlp blocks dispatch FIRST so their work fills gram's latency-stall cycles;
// gram blocks start at bid=MLPB (288 % 8 == 0, preserving the XCD swizzle).
__global__ __launch_bounds__(256, 2) void fused_main(
    const unsigned char* __restrict__ fbT, const float* __restrict__ sL,
    const float* __restrict__ pL, const float* __restrict__ f,
    const unsigned short* __restrict__ W1t, const float* __restrict__ scores,
    const float* __restrict__ W1, const float* __restrict__ b1,
    const float* __restrict__ g1, const float* __restrict__ be1,
    const float* __restrict__ W2, const float* __restrict__ b2,
    const float* __restrict__ g2, const float* __restrict__ be2,
    const float* __restrict__ W3, const float* __restrict__ b3,
    double* __restrict__ sums, unsigned* __restrict__ ctr,
    float* __restrict__ out) {
  // LDS union: mlp layout (51584 B) overlays gram layout (3088 B).
  // 51.6 KB/block -> 3 blocks/CU LDS-wise, above gram's 2-block register cap.
  __shared__ __align__(16) char smem[51584];
  int bid = blockIdx.x, t = threadIdx.x, lane = t & 63, wave = t >> 6;

  if (bid < MLPB) {
    // ================= MLP path: 32 rows/block, BK=64 =================
    int r0 = bid * 32;
    float* As32 = (float*)smem;                       // 32*64 f, 16-slot XOR swz
    unsigned short* Bs = (unsigned short*)(smem + 8192);  // 128*64 bf16, 8-slot
    float (*h1s)[128] = (float (*)[128])(smem + 24576);
    float (*h2s)[65]  = (float (*)[65])(smem + 40960);
    float* sc   = (float*)(smem + 49280);
    float* b1s  = (float*)(smem + 49408);
    float* g1s  = (float*)(smem + 49920);
    float* be1s = (float*)(smem + 50432);
    float* wls  = (float*)(smem + 50944);
    float* ls   = (float*)(smem + 51456);

    if (t < 32) sc[t] = scores[r0 + t];
    if (t < 128) {
      b1s[t] = b1[t]; g1s[t] = g1[t]; be1s[t] = be1[t];
      wls[t] = W1[(size_t)DFEAT * 128 + t];
    }

    floatx4 acc[4];
#pragma unroll
    for (int b = 0; b < 4; b++) acc[b] = (floatx4){0.f, 0.f, 0.f, 0.f};

    const int wr = (wave & 1) * 16, wc = (wave >> 1) * 64;

    for (int k0 = 0; k0 < DFEAT; k0 += 64) {
      __syncthreads();
      {
        // A: 512 chunks (32 rows x 16/row); phys p of row r holds logical p^(r&15)
        int c = t, rA = c >> 4, p = c & 15, l = p ^ (rA & 15);
        async_copy16(f + (size_t)(r0 + rA) * DFEAT + k0 + l * 4, (char*)As32 + c * 16);
        c = t + 256; rA = c >> 4; p = c & 15; l = p ^ (rA & 15);
        async_copy16(f + (size_t)(r0 + rA) * DFEAT + k0 + l * 4, (char*)As32 + c * 16);
        // B: 1024 chunks (128 rows x 8/row); phys p holds logical p^(r&7)
#pragma unroll
        for (int q = 0; q < 4; q++) {
          int cc = t + q * 256, rB = cc >> 3, pp = cc & 7, ll = pp ^ (rB & 7);
          async_copy16(W1t + (size_t)rB * DFEAT + k0 + ll * 8, (char*)Bs + cc * 16);
        }
      }
      __syncthreads();

      const int mrow = lane & 15;
#pragma unroll
      for (int ks = 0; ks < 2; ks++) {
        const int kq = ks * 32 + (lane >> 4) * 8;
        short8 a, b[4];
        {
          int row = wr + mrow;
          int l0 = kq >> 2;
          int p0 = l0 ^ (row & 15), p1 = (l0 + 1) ^ (row & 15);
          float4 f0 = *(const float4*)&As32[row * 64 + p0 * 4];
          float4 f1 = *(const float4*)&As32[row * 64 + p1 * 4];
          a[0] = (short)f2bf(f0.x); a[1] = (short)f2bf(f0.y);
          a[2] = (short)f2bf(f0.z); a[3] = (short)f2bf(f0.w);
          a[4] = (short)f2bf(f1.x); a[5] = (short)f2bf(f1.y);
          a[6] = (short)f2bf(f1.z); a[7] = (short)f2bf(f1.w);
        }
#pragma unroll
        for (int nt = 0; nt < 4; nt++) {
          int row = wc + nt * 16 + mrow;
          int p = (kq >> 3) ^ (row & 7);
          b[nt] = *(const short8*)&Bs[row * 64 + p * 8];
        }
#pragma unroll
        for (int nt = 0; nt < 4; nt++)
          acc[nt] = __builtin_amdgcn_mfma_f32_16x16x32_bf16(a, b[nt], acc[nt], 0, 0, 0);
      }
    }

    const float inv = 1.0f / sqrtf(1.0f + 1e-5f);
    const int rq = (lane >> 4) * 4, cn = lane & 15;
#pragma unroll
    for (int nt = 0; nt < 4; nt++) {
      int j = wc + nt * 16 + cn;
      float bj = b1s[j], gj = g1s[j] * inv, bej = be1s[j], wj = wls[j];
#pragma unroll
      for (int rr = 0; rr < 4; rr++) {
        int iL = wr + rq + rr;
        float pre = acc[nt][rr] + sc[iL] * wj + bj;
        h1s[iL][j] = fmaxf(gj * pre + bej, 0.f);
      }
    }
    __syncthreads();

    // layer 2: 128 -> 64. j = t&63, 8 rows/thread (broadcast LDS reads)
    {
      int j = t & 63, rg = (t >> 6) * 8;
      float a2[8];
#pragma unroll
      for (int rr = 0; rr < 8; rr++) a2[rr] = 0.f;
      for (int k = 0; k < 128; k++) {
        float w = W2[k * 64 + j];
#pragma unroll
        for (int rr = 0; rr < 8; rr++) a2[rr] = fmaf(h1s[rg + rr][k], w, a2[rr]);
      }
      float scv = g2[j] * inv, bi = b2[j], be = be2[j];
#pragma unroll
      for (int rr = 0; rr < 8; rr++)
        h2s[rg + rr][j] = fmaxf(scv * (a2[rr] + bi) + be, 0.f);
    }
    __syncthreads();

    // layer 3: 64 -> 1 + sigmoid
    if (t < 32) {
      float z = b3[0];
#pragma unroll
      for (int k = 0; k < 64; k++) z = fmaf(h2s[t][k], W3[k], z);
      ls[t] = 1.f / (1.f + __expf(-z));
    }
    __syncthreads();
    if (t == 0) {
      float s = 0.f;
#pragma unroll
      for (int iL = 0; iL < 32; iL++) s += ls[iL];
      atomicAdd(&sums[1], (double)s);
    }
  } else {
    // ============ GRAM path: MX-fp4 MFMA, direct-global frags ============
    int gb = bid - MLPB;
    // XCD-contiguous mapping: consecutive logical L on the same XCD (gb%8)
    int x = gb & 7, ii = gb >> 3;
    int L = (x < 4) ? x * 167 + ii : 668 + (x - 4) * 166 + ii;
    // decode L -> (bcol, brow), brow < min(72, 2*bcol+2); bcol-major (B L2-hot)
    int rem = L, bcol = 0;
    for (;;) {
      int mlim = 2 * bcol + 2; if (mlim > NBR) mlim = NBR;
      if (rem < mlim) break;
      rem -= mlim; bcol++;
    }
    int brow = rem;

    float* sA = (float*)smem;            // 128
    float* pA = (float*)(smem + 512);    // 128
    float* sB = (float*)(smem + 1024);   // 256
    float* pB = (float*)(smem + 2048);   // 256
    float* wpart = (float*)(smem + 3072);

    if (t < 128) { sA[t] = sL[brow * 128 + t]; pA[t] = pL[brow * 128 + t]; }
    sB[t] = sL[bcol * 256 + t];
    pB[t] = pL[bcol * 256 + t];
    __syncthreads();

    const int wr = (wave & 1) * 64, wc = (wave >> 1) * 128;
    const int r32 = lane & 31, kh = lane >> 5;
    const int loff = r32 * 32 + kh * 16;

    const unsigned char* pa0 = fbT + (size_t)(brow * 4 + (wr >> 5)) * 16384 + loff;
    const unsigned char* pa1 = pa0 + 16384;
    const unsigned char* pb0 = fbT + (size_t)(bcol * 8 + (wc >> 5)) * 16384 + loff;
    const unsigned char* pb1 = pb0 + 16384;
    const unsigned char* pb2 = pb0 + 32768;
    const unsigned char* pb3 = pb0 + 49152;

    floatx16 acc[2][4];
#pragma unroll
    for (int mi = 0; mi < 2; mi++)
#pragma unroll
      for (int ni = 0; ni < 4; ni++)
#pragma unroll
        for (int e = 0; e < 16; e++) acc[mi][ni][e] = 0.f;

    // depth-2 software pipeline: 3 register buffer sets, loads 2 iters ahead
    intx4 bA[3][2], bB[3][4];
#define LDSET(s, kb)                                                          \
    {                                                                         \
      const int o = (kb) * 1024;                                              \
      bA[s][0] = *(const intx4*)(pa0 + o); bA[s][1] = *(const intx4*)(pa1 + o); \
      bB[s][0] = *(const intx4*)(pb0 + o); bB[s][1] = *(const intx4*)(pb1 + o); \
      bB[s][2] = *(const intx4*)(pb2 + o); bB[s][3] = *(const intx4*)(pb3 + o); \
    }
    LDSET(0, 0)
    LDSET(1, 1)
#pragma unroll
    for (int kb = 0; kb < 16; kb++) {
      const int cur = kb % 3, nxt = (kb + 2) % 3;
      if (kb < 14) LDSET(nxt, kb + 2)
      intx8 A8[2], B8[4];
#pragma unroll
      for (int mi = 0; mi < 2; mi++) A8[mi] = ext8(bA[cur][mi]);
#pragma unroll
      for (int ni = 0; ni < 4; ni++) B8[ni] = ext8(bB[cur][ni]);
#pragma unroll
      for (int mi = 0; mi < 2; mi++)
#pragma unroll
        for (int ni = 0; ni < 4; ni++)
          acc[mi][ni] = __builtin_amdgcn_mfma_scale_f32_32x32x64_f8f6f4(
              A8[mi], B8[ni], acc[mi][ni], 4, 4,       // FMT fp4 / fp4
              0, 0x7F7F7F7F, 0, 0x7F7F7F7F);           // scales = 1.0
    }
#undef LDSET

    // epilogue: g ~= 1024*cos. C/D layout col=lane&31, row=(reg&3)+8*(reg>>2)+4*kh
    const bool interior = (brow < 2 * bcol);
    float lsum = 0.f;
#pragma unroll
    for (int ni = 0; ni < 4; ni++) {
      int j_loc = wc + ni * 32 + r32;
      float sj = sB[j_loc], pj = pB[j_loc];
      int j_g = bcol * 256 + j_loc;
#pragma unroll
      for (int mi = 0; mi < 2; mi++) {
        int rbase = wr + mi * 32 + 4 * kh;
#pragma unroll
        for (int reg = 0; reg < 16; reg++) {
          int i_loc = rbase + (reg & 3) + 8 * (reg >> 2);
          float g = acc[mi][ni][reg];
          float si = sA[i_loc], pi = pA[i_loc];
          float r = __builtin_amdgcn_rcpf(1024.f + g);
          float del = pi * pj;
          float gam = si + sj + del;
          float tt = gam * r;
          float sim = __builtin_amdgcn_exp2f(fmaf(-1024.f, tt, del));
          if (interior) {
            lsum += sim;
          } else {
            int i_g = brow * 128 + i_loc;
            lsum += (i_g < j_g) ? 2.f * sim : (i_g == j_g ? 1.f : 0.f);
          }
        }
      }
    }
    if (interior) lsum *= 2.f;
#pragma unroll
    for (int off = 32; off > 0; off >>= 1) lsum += __shfl_down(lsum, off, 64);
    if (lane == 0) wpart[wave] = lsum;
    __syncthreads();
    if (t == 0)
      atomicAdd(&sums[0], (double)(wpart[0] + wpart[1] + wpart[2] + wpart[3]));
  }

  // ---- folded finalize: last block to finish combines the two sums ----
  if (t == 0) {
    __threadfence();                               // make my sums atomic visible
    unsigned prev = atomicAdd(ctr, 1u);
    if (prev == (unsigned)(NGRID - 1)) {
      __threadfence();
      double s0 = ((volatile double*)sums)[0];
      double s1 = ((volatile double*)sums)[1];
      out[0] = (float)((s1 / (double)N_IMG) * (s0 / ((double)N_IMG * (double)N_IMG)));
    }
  }
}

extern "C" void kernel_launch(void* const* d_in, const int* in_sizes, int n_in,
                              void* d_out, int out_size, void* d_ws, size_t ws_size,
                              hipStream_t stream) {
  const float* f      = (const float*)d_in[0];
  const float* scores = (const float*)d_in[1];
  const float* W1 = (const float*)d_in[2];
  const float* b1 = (const float*)d_in[3];
  const float* g1 = (const float*)d_in[4];
  const float* be1 = (const float*)d_in[5];
  const float* W2 = (const float*)d_in[6];
  const float* b2 = (const float*)d_in[7];
  const float* g2 = (const float*)d_in[8];
  const float* be2 = (const float*)d_in[9];
  const float* W3 = (const float*)d_in[10];
  const float* b3 = (const float*)d_in[11];

  // workspace layout (~5.06 MB total)
  char* ws = (char*)d_ws;
  unsigned char* fbT  = (unsigned char*)ws;                  // 4,718,592 B (fp4 tiled)
  float* sL           = (float*)(ws + 4718592);              // 36,864 B  (s * C1)
  float* pL           = (float*)(ws + 4755456);              // 36,864 B  (sqrt(s) * C2)
  unsigned short* W1t = (unsigned short*)(ws + 4792320);     // 262,144 B
  double* sums        = (double*)(ws + 5054464);             // 16 B
  unsigned* ctr       = (unsigned*)(ws + 5054480);           // 4 B (completion)

  convert_prep<<<2432, 256, 0, stream>>>(f, W1, fbT, sL, pL, W1t, sums, ctr);
  fused_main<<<NGRID, 256, 0, stream>>>(fbT, sL, pL, f, W1t, scores,
                                        W1, b1, g1, be1, W2, b2, g2, be2, W3, b3,
                                        sums, ctr, (float*)d_out);
}

// Round 2
// 193.555 us; speedup vs baseline: 1.0704x; 1.0704x over previous
//
#include <hip/hip_runtime.h>

#define N_IMG 9216
#define DFEAT 1024
#define NBP 36           // 256-row panels
#define NPAIR2 666       // 36*37/2 triangular block-pairs

typedef __attribute__((ext_vector_type(8))) short short8;
typedef __attribute__((ext_vector_type(4))) float floatx4;
typedef __attribute__((ext_vector_type(16))) float floatx16;
typedef __attribute__((ext_vector_type(4))) int intx4;
typedef __attribute__((ext_vector_type(8))) int intx8;

// exp2-folded constants: sim = exp2(delta - gamma * rcp(1+u))
//   delta_ij = Pi*Pj          (P = sqrt(s) * C2, C2 = sqrt(2*log2e/1024))
//   gamma_ij = s~i + s~j + delta_ij   (s~ = s * C1, C1 = log2e/1024)
// fp4 path: Gram g = sum(z_i z_j), z = 32*normalized -> u = g/1024;
// rcp(1+u) = 1024*rcp(1024+g).
#define C1F 0.0014088818759657845f
#define C2F 0.05308355472172724f

__device__ __forceinline__ void async_copy16(const void* g, void* l) {
  __builtin_amdgcn_global_load_lds((const __attribute__((address_space(1))) void*)g,
                                   (__attribute__((address_space(3))) void*)l,
                                   16, 0, 0);
}

__device__ __forceinline__ unsigned short f2bf(float x) {
  union { float f; unsigned u; } a; a.f = x;
  unsigned u = a.u;
  u += 0x7fffu + ((u >> 16) & 1u);   // round-to-nearest-even
  return (unsigned short)(u >> 16);
}

// ---- fp4 e2m1 quantizer (RNE midpoints), values {0,.5,1,1.5,2,3,4,6} ----
__device__ __forceinline__ unsigned q4(float z) {
  unsigned sg = (__float_as_uint(z) >> 28) & 8u;
  float a = fabsf(z);
  unsigned c = (a < 0.25f) ? 0u : (a < 0.75f) ? 1u : (a < 1.25f) ? 2u :
               (a < 1.75f) ? 3u : (a < 2.5f)  ? 4u : (a < 3.5f)  ? 5u :
               (a < 5.0f)  ? 6u : 7u;
  return c | sg;
}
__device__ __forceinline__ unsigned short pk4(float4 v, float sc) {
  unsigned b0 = q4(v.x * sc) | (q4(v.y * sc) << 4);
  unsigned b1 = q4(v.z * sc) | (q4(v.w * sc) << 4);
  return (unsigned short)(b0 | (b1 << 8));
}

// ---- kernel 1: fp32 -> fp4 fragment-tiled + s~/P; also W1^T bf16; init sums ----
// tiled layout: fbT[rt][kb][r32][32B], rt=row>>5 (288 tiles), kb=k>>6 (16),
// r32=row&31. 16B-half within the 32B row is XOR-swizzled by (r32>>2)&1 so that
// gram's stride-32B ds_read_b128 frag reads hit the optimal 4-way bank aliasing.
__global__ __launch_bounds__(256) void convert_prep(const float* __restrict__ f,
                                                    const float* __restrict__ W1,
                                                    unsigned char* __restrict__ fbT,
                                                    float* __restrict__ sL,
                                                    float* __restrict__ pL,
                                                    unsigned short* __restrict__ W1t,
                                                    double* __restrict__ sums,
                                                    unsigned* __restrict__ ctr) {
  int b = blockIdx.x, t = threadIdx.x;
  if (b < 2304) {
    int lane = t & 63, wave = t >> 6;
    int row = b * 4 + wave;                      // one wave per row
    const float4* src = (const float4*)f + (size_t)row * 256;
    float4 v0 = src[lane], v1 = src[64 + lane], v2 = src[128 + lane], v3 = src[192 + lane];
    float s = v0.x * v0.x + v0.y * v0.y + v0.z * v0.z + v0.w * v0.w
            + v1.x * v1.x + v1.y * v1.y + v1.z * v1.z + v1.w * v1.w
            + v2.x * v2.x + v2.y * v2.y + v2.z * v2.z + v2.w * v2.w
            + v3.x * v3.x + v3.y * v3.y + v3.z * v3.z + v3.w * v3.w;
#pragma unroll
    for (int off = 32; off > 0; off >>= 1) s += __shfl_xor(s, off, 64);
    float zsc = rsqrtf(s) * 32.f;                // z ~ N(0,1)
    unsigned short u0 = pk4(v0, zsc), u1 = pk4(v1, zsc),
                   u2 = pk4(v2, zsc), u3 = pk4(v3, zsc);
    // lane holds elems 256j+4*lane..+3 -> kb_j = 4j + (lane>>4);
    // within-row byte = swizzled-half*16 + 2*(e&7), e = lane&15, half = e>>3
    unsigned e = lane & 15;
    unsigned sw = (row >> 2) & 1;                // = (r32>>2)&1
    unsigned char* tb = fbT + (size_t)(row >> 5) * 16384 + (row & 31) * 32
                      + (((e >> 3) ^ sw) * 16) + (e & 7) * 2;
    int ko = (lane >> 4) * 1024;
    *(unsigned short*)(tb + ko) = u0;
    *(unsigned short*)(tb + ko + 4096) = u1;
    *(unsigned short*)(tb + ko + 8192) = u2;
    *(unsigned short*)(tb + ko + 12288) = u3;
    if (lane == 0) {
      sL[row] = s * C1F;
      pL[row] = sqrtf(s) * C2F;
    }
  } else {
    int j = b - 2304;                            // W1 column j -> W1t row j
    if (j == 0) {
      if (t < 2) sums[t] = 0.0;
      if (t == 2) *ctr = 0u;                     // completion counter for mlp
    }
    for (int k = t; k < DFEAT; k += 256)
      W1t[(size_t)j * DFEAT + k] = f2bf(W1[(size_t)k * 128 + j]);
  }
}

// ---- kernel 2: Gram via MX-fp4 MFMA, 256x256 LDS-staged tiles ----
// 8 waves/block; wave (m,n) = ((wave&1), wave>>1) owns a 128x64 sub-tile.
// Per K-step (K=64): 16 KB staged via global_load_lds (2 slabs/wave),
// double-buffered with counted s_waitcnt vmcnt(2) (prefetch alive across
// barriers). Each panel row is fetched ONCE per block from L2/L3 (was 2-3x
// redundant in the direct-from-global version).
__global__ __launch_bounds__(512, 2) void gram_sim(const unsigned char* __restrict__ fbT,
                                                   const float* __restrict__ sL,
                                                   const float* __restrict__ pL,
                                                   double* __restrict__ sums) {
  __shared__ __align__(16) unsigned char stg[2][16384];  // [buf][A 8KB | B 8KB]
  __shared__ float sA[256], pA[256], sB[256], pB[256];
  __shared__ float wpart[8];

  int bid = blockIdx.x, t = threadIdx.x, lane = t & 63, wave = t >> 6;
  // bijective XCD swizzle (666 = 8*83 + 2): consecutive L share an XCD chunk
  int xcd = bid & 7, t8 = bid >> 3;
  int L = (xcd < 2 ? xcd * 84 : 168 + (xcd - 2) * 83) + t8;
  // decode triangular, bcol-major (B-panel L2-hot): panel bcol has bcol+1 rows
  int rem = L, bcol = 0;
  while (rem > bcol) { rem -= (bcol + 1); bcol++; }
  int brow = rem;                                 // brow <= bcol

  if (t < 256) { sA[t] = sL[brow * 256 + t]; pA[t] = pL[brow * 256 + t]; }
  else { int u = t & 255; sB[u] = sL[bcol * 256 + u]; pB[u] = pL[bcol * 256 + u]; }

  // staging: wave w copies slabs {2w, 2w+1}: w<4 from A panel, w>=4 from B panel
  const int spanel = (wave < 4) ? brow : bcol;
  const int slab0 = (wave < 4) ? (2 * wave) : (2 * wave - 8);
  const unsigned char* src0 = fbT + (size_t)(spanel * 8 + slab0) * 16384 + lane * 16;
  const unsigned char* src1 = src0 + 16384;
  char* dst0 = (char*)stg + wave * 2048 + lane * 16;   // A region 0..8K, B 8K..16K

#define STAGE(buf, kb)                                              \
  {                                                                 \
    async_copy16(src0 + (kb) * 1024, dst0 + (buf) * 16384);         \
    async_copy16(src1 + (kb) * 1024, dst0 + 1024 + (buf) * 16384);  \
  }

  const int r32 = lane & 31, kh = lane >> 5;
  const int swz = (r32 >> 2) & 1;                 // matches convert_prep's XOR
  const int loff = r32 * 32 + ((kh ^ swz) << 4);
  const int wr = (wave & 1) * 128, wc = (wave >> 1) * 64;
  const char* aBase = (const char*)stg + ((wave & 1) * 4) * 1024 + loff;
  const char* bBase = (const char*)stg + 8192 + ((wave >> 1) * 2) * 1024 + loff;

  floatx16 acc[4][2];
#pragma unroll
  for (int mi = 0; mi < 4; mi++)
#pragma unroll
    for (int ni = 0; ni < 2; ni++)
#pragma unroll
      for (int e = 0; e < 16; e++) acc[mi][ni][e] = 0.f;

  intx8 A8[4], B8[2];                             // high 4 regs stay zero (fp4)
#pragma unroll
  for (int mi = 0; mi < 4; mi++)
#pragma unroll
    for (int e = 0; e < 8; e++) A8[mi][e] = 0;
#pragma unroll
  for (int ni = 0; ni < 2; ni++)
#pragma unroll
    for (int e = 0; e < 8; e++) B8[ni][e] = 0;

  STAGE(0, 0)
  STAGE(1, 1)                                     // 4 loads outstanding / wave
#pragma unroll
  for (int kb = 0; kb < 16; kb++) {
    if (kb < 15) asm volatile("s_waitcnt vmcnt(2)" ::: "memory");
    else         asm volatile("s_waitcnt vmcnt(0)" ::: "memory");
    __builtin_amdgcn_s_barrier();                 // everyone's kb stage visible
    __builtin_amdgcn_sched_barrier(0);            // pin ds_reads below barrier
    const int cur = (kb & 1) * 16384;
#pragma unroll
    for (int mi = 0; mi < 4; mi++) {
      intx4 v = *(const intx4*)(aBase + cur + mi * 1024);
      A8[mi][0] = v[0]; A8[mi][1] = v[1]; A8[mi][2] = v[2]; A8[mi][3] = v[3];
    }
#pragma unroll
    for (int ni = 0; ni < 2; ni++) {
      intx4 v = *(const intx4*)(bBase + cur + ni * 1024);
      B8[ni][0] = v[0]; B8[ni][1] = v[1]; B8[ni][2] = v[2]; B8[ni][3] = v[3];
    }
#pragma unroll
    for (int mi = 0; mi < 4; mi++)
#pragma unroll
      for (int ni = 0; ni < 2; ni++)
        acc[mi][ni] = __builtin_amdgcn_mfma_scale_f32_32x32x64_f8f6f4(
            A8[mi], B8[ni], acc[mi][ni], 4, 4,    // FMT fp4 / fp4
            0, 0x7F7F7F7F, 0, 0x7F7F7F7F);        // scales = 1.0
    __builtin_amdgcn_s_barrier();                 // all reads of buf done
    __builtin_amdgcn_sched_barrier(0);            // pin stage below barrier
    if (kb < 14) STAGE((kb & 1), kb + 2)
  }
#undef STAGE

  // epilogue: g ~= 1024*cos. C/D layout col=lane&31, row=(reg&3)+8*(reg>>2)+4*kh
  const bool diag = (brow == bcol);
  float lsum = 0.f;
#pragma unroll
  for (int ni = 0; ni < 2; ni++) {
    int j_loc = wc + ni * 32 + r32;
    float sj = sB[j_loc], pj = pB[j_loc];
#pragma unroll
    for (int mi = 0; mi < 4; mi++) {
      int rbase = wr + mi * 32 + 4 * kh;
#pragma unroll
      for (int reg = 0; reg < 16; reg++) {
        int i_loc = rbase + (reg & 3) + 8 * (reg >> 2);
        float g = acc[mi][ni][reg];
        float si = sA[i_loc], pi = pA[i_loc];
        float r = __builtin_amdgcn_rcpf(1024.f + g);
        float del = pi * pj;
        float gam = si + sj + del;
        float sim = __builtin_amdgcn_exp2f(fmaf(-1024.f, gam * r, del));
        if (!diag) {
          lsum += sim;
        } else {
          lsum += (i_loc < j_loc) ? 2.f * sim : (i_loc == j_loc ? 1.f : 0.f);
        }
      }
    }
  }
  if (!diag) lsum *= 2.f;                         // brow<bcol: all i<j, count x2
#pragma unroll
  for (int off = 32; off > 0; off >>= 1) lsum += __shfl_down(lsum, off, 64);
  if (lane == 0) wpart[wave] = lsum;
  __syncthreads();
  if (t == 0) {
    float bs = 0.f;
#pragma unroll
    for (int w = 0; w < 8; w++) bs += wpart[w];
    atomicAdd(&sums[0], (double)bs);
  }
}

// ---- kernel 3: full MLP, 32 rows/block (288 blocks); folds finalize ----
__global__ __launch_bounds__(256) void mlp_full(const float* __restrict__ f,
                                                const unsigned short* __restrict__ W1t,
                                                const float* __restrict__ scores,
                                                const float* __restrict__ W1,
                                                const float* __restrict__ b1,
                                                const float* __restrict__ g1,
                                                const float* __restrict__ be1,
                                                const float* __restrict__ W2, const float* __restrict__ b2,
                                                const float* __restrict__ g2, const float* __restrict__ be2,
                                                const float* __restrict__ W3, const float* __restrict__ b3,
                                                double* __restrict__ sums,
                                                unsigned* __restrict__ ctr,
                                                float* __restrict__ out) {
  int r0 = blockIdx.x * 32;

  __shared__ __align__(16) float As32[32 * 64];         // 8 KB, 16-slot XOR swizzle
  __shared__ __align__(16) unsigned short Bs[128 * 64]; // 16 KB, 8-slot XOR swizzle
  __shared__ float h1s[32][128];                        // 16 KB
  __shared__ float h2s[32][65];                         // 8.3 KB
  __shared__ float sc[32], b1s[128], g1s[128], be1s[128], wls[128], ls[32];

  int t = threadIdx.x, lane = t & 63, wave = t >> 6;
  if (t < 32) sc[t] = scores[r0 + t];
  if (t < 128) {
    b1s[t] = b1[t]; g1s[t] = g1[t]; be1s[t] = be1[t];
    wls[t] = W1[(size_t)DFEAT * 128 + t];
  }

  floatx4 acc[4];
#pragma unroll
  for (int b = 0; b < 4; b++) acc[b] = (floatx4){0.f, 0.f, 0.f, 0.f};

  const int wr = (wave & 1) * 16, wc = (wave >> 1) * 64;

  for (int k0 = 0; k0 < DFEAT; k0 += 64) {
    __syncthreads();
    {
      // A: 512 chunks (32 rows x 16/row); phys p of row r holds logical p^(r&15)
      int c = t, rA = c >> 4, p = c & 15, l = p ^ (rA & 15);
      async_copy16(f + (size_t)(r0 + rA) * DFEAT + k0 + l * 4, (char*)As32 + c * 16);
      c = t + 256; rA = c >> 4; p = c & 15; l = p ^ (rA & 15);
      async_copy16(f + (size_t)(r0 + rA) * DFEAT + k0 + l * 4, (char*)As32 + c * 16);
      // B: 1024 chunks (128 rows x 8/row); phys p holds logical p^(r&7)
#pragma unroll
      for (int q = 0; q < 4; q++) {
        int cc = t + q * 256, rB = cc >> 3, pp = cc & 7, ll = pp ^ (rB & 7);
        async_copy16(W1t + (size_t)rB * DFEAT + k0 + ll * 8, (char*)Bs + cc * 16);
      }
    }
    __syncthreads();

    const int mrow = lane & 15;
#pragma unroll
    for (int ks = 0; ks < 2; ks++) {
      const int kq = ks * 32 + (lane >> 4) * 8;
      short8 a, b[4];
      {
        int row = wr + mrow;
        int l0 = kq >> 2;
        int p0 = l0 ^ (row & 15), p1 = (l0 + 1) ^ (row & 15);
        float4 f0 = *(const float4*)&As32[row * 64 + p0 * 4];
        float4 f1 = *(const float4*)&As32[row * 64 + p1 * 4];
        a[0] = (short)f2bf(f0.x); a[1] = (short)f2bf(f0.y);
        a[2] = (short)f2bf(f0.z); a[3] = (short)f2bf(f0.w);
        a[4] = (short)f2bf(f1.x); a[5] = (short)f2bf(f1.y);
        a[6] = (short)f2bf(f1.z); a[7] = (short)f2bf(f1.w);
      }
#pragma unroll
      for (int nt = 0; nt < 4; nt++) {
        int row = wc + nt * 16 + mrow;
        int p = (kq >> 3) ^ (row & 7);
        b[nt] = *(const short8*)&Bs[row * 64 + p * 8];
      }
#pragma unroll
      for (int nt = 0; nt < 4; nt++)
        acc[nt] = __builtin_amdgcn_mfma_f32_16x16x32_bf16(a, b[nt], acc[nt], 0, 0, 0);
    }
  }

  const float inv = 1.0f / sqrtf(1.0f + 1e-5f);
  const int rq = (lane >> 4) * 4, cn = lane & 15;
#pragma unroll
  for (int nt = 0; nt < 4; nt++) {
    int j = wc + nt * 16 + cn;
    float bj = b1s[j], gj = g1s[j] * inv, bej = be1s[j], wj = wls[j];
#pragma unroll
    for (int rr = 0; rr < 4; rr++) {
      int iL = wr + rq + rr;
      float pre = acc[nt][rr] + sc[iL] * wj + bj;
      h1s[iL][j] = fmaxf(gj * pre + bej, 0.f);
    }
  }
  __syncthreads();

  // layer 2: 128 -> 64. j = t&63, 8 rows/thread (broadcast LDS reads)
  {
    int j = t & 63, rg = (t >> 6) * 8;
    float a2[8];
#pragma unroll
    for (int rr = 0; rr < 8; rr++) a2[rr] = 0.f;
    for (int k = 0; k < 128; k++) {
      float w = W2[k * 64 + j];
#pragma unroll
      for (int rr = 0; rr < 8; rr++) a2[rr] = fmaf(h1s[rg + rr][k], w, a2[rr]);
    }
    float scv = g2[j] * inv, bi = b2[j], be = be2[j];
#pragma unroll
    for (int rr = 0; rr < 8; rr++)
      h2s[rg + rr][j] = fmaxf(scv * (a2[rr] + bi) + be, 0.f);
  }
  __syncthreads();

  // layer 3: 64 -> 1 + sigmoid
  if (t < 32) {
    float z = b3[0];
#pragma unroll
    for (int k = 0; k < 64; k++) z = fmaf(h2s[t][k], W3[k], z);
    ls[t] = 1.f / (1.f + __expf(-z));
  }
  __syncthreads();
  if (t == 0) {
    float s = 0.f;
#pragma unroll
    for (int iL = 0; iL < 32; iL++) s += ls[iL];
    atomicAdd(&sums[1], (double)s);
    // folded finalize: gram ran earlier in-stream, so sums[0] is complete;
    // last mlp block to arrive combines.
    __threadfence();
    unsigned prev = atomicAdd(ctr, 1u);
    if (prev == 287u) {
      __threadfence();
      double s0 = ((volatile double*)sums)[0];
      double s1 = ((volatile double*)sums)[1];
      out[0] = (float)((s1 / (double)N_IMG) * (s0 / ((double)N_IMG * (double)N_IMG)));
    }
  }
}

extern "C" void kernel_launch(void* const* d_in, const int* in_sizes, int n_in,
                              void* d_out, int out_size, void* d_ws, size_t ws_size,
                              hipStream_t stream) {
  const float* f      = (const float*)d_in[0];
  const float* scores = (const float*)d_in[1];
  const float* W1 = (const float*)d_in[2];
  const float* b1 = (const float*)d_in[3];
  const float* g1 = (const float*)d_in[4];
  const float* be1 = (const float*)d_in[5];
  const float* W2 = (const float*)d_in[6];
  const float* b2 = (const float*)d_in[7];
  const float* g2 = (const float*)d_in[8];
  const float* be2 = (const float*)d_in[9];
  const float* W3 = (const float*)d_in[10];
  const float* b3 = (const float*)d_in[11];

  // workspace layout (~5.06 MB total)
  char* ws = (char*)d_ws;
  unsigned char* fbT  = (unsigned char*)ws;                  // 4,718,592 B (fp4 tiled)
  float* sL           = (float*)(ws + 4718592);              // 36,864 B  (s * C1)
  float* pL           = (float*)(ws + 4755456);              // 36,864 B  (sqrt(s) * C2)
  unsigned short* W1t = (unsigned short*)(ws + 4792320);     // 262,144 B
  double* sums        = (double*)(ws + 5054464);             // 16 B
  unsigned* ctr       = (unsigned*)(ws + 5054480);           // 4 B (completion)

  convert_prep<<<2432, 256, 0, stream>>>(f, W1, fbT, sL, pL, W1t, sums, ctr);
  gram_sim<<<NPAIR2, 512, 0, stream>>>(fbT, sL, pL, sums);
  mlp_full<<<288, 256, 0, stream>>>(f, W1t, scores, W1, b1, g1, be1,
                                    W2, b2, g2, be2, W3, b3, sums, ctr,
                                    (float*)d_out);
}

// Round 3
// 187.298 us; speedup vs baseline: 1.1061x; 1.0334x over previous
//
#include <hip/hip_runtime.h>

#define N_IMG 9216
#define DFEAT 1024
#define NBP 36           // 256-row panels
#define NPAIR2 666       // 36*37/2 triangular block-pairs

typedef __attribute__((ext_vector_type(8))) short short8;
typedef __attribute__((ext_vector_type(4))) float floatx4;
typedef __attribute__((ext_vector_type(16))) float floatx16;
typedef __attribute__((ext_vector_type(4))) int intx4;
typedef __attribute__((ext_vector_type(8))) int intx8;

// exp2-folded constants: sim = exp2(delta - gamma * rcp(1+u))
//   delta_ij = Pi*Pj          (P = sqrt(s) * C2, C2 = sqrt(2*log2e/1024))
//   gamma_ij = s~i + s~j + delta_ij   (s~ = s * C1, C1 = log2e/1024)
// fp4 path: Gram g = sum(z_i z_j), z = 32*normalized -> u = g/1024;
// rcp(1+u) = 1024*rcp(1024+g).
#define C1F 0.0014088818759657845f
#define C2F 0.05308355472172724f

__device__ __forceinline__ void async_copy16(const void* g, void* l) {
  __builtin_amdgcn_global_load_lds((const __attribute__((address_space(1))) void*)g,
                                   (__attribute__((address_space(3))) void*)l,
                                   16, 0, 0);
}

__device__ __forceinline__ unsigned short f2bf(float x) {
  union { float f; unsigned u; } a; a.f = x;
  unsigned u = a.u;
  u += 0x7fffu + ((u >> 16) & 1u);   // round-to-nearest-even
  return (unsigned short)(u >> 16);
}

// ---- fp4 e2m1 quantizer (RNE midpoints), values {0,.5,1,1.5,2,3,4,6} ----
__device__ __forceinline__ unsigned q4(float z) {
  unsigned sg = (__float_as_uint(z) >> 28) & 8u;
  float a = fabsf(z);
  unsigned c = (a < 0.25f) ? 0u : (a < 0.75f) ? 1u : (a < 1.25f) ? 2u :
               (a < 1.75f) ? 3u : (a < 2.5f)  ? 4u : (a < 3.5f)  ? 5u :
               (a < 5.0f)  ? 6u : 7u;
  return c | sg;
}
__device__ __forceinline__ unsigned short pk4(float4 v, float sc) {
  unsigned b0 = q4(v.x * sc) | (q4(v.y * sc) << 4);
  unsigned b1 = q4(v.z * sc) | (q4(v.w * sc) << 4);
  return (unsigned short)(b0 | (b1 << 8));
}

// ---- kernel 1: fp32 -> fp4 fragment-tiled + s~/P; also W1^T bf16; init sums ----
// tiled layout: fbT[rt][kb][r32][32B], rt=row>>5 (288 tiles), kb=k>>6 (16),
// r32=row&31; one (rt,kb) slab-chunk = 1024 B = one wave's coalesced frag.
__global__ __launch_bounds__(256) void convert_prep(const float* __restrict__ f,
                                                    const float* __restrict__ W1,
                                                    unsigned char* __restrict__ fbT,
                                                    float* __restrict__ sL,
                                                    float* __restrict__ pL,
                                                    unsigned short* __restrict__ W1t,
                                                    double* __restrict__ sums,
                                                    unsigned* __restrict__ ctr) {
  int b = blockIdx.x, t = threadIdx.x;
  if (b < 2304) {
    int lane = t & 63, wave = t >> 6;
    int row = b * 4 + wave;                      // one wave per row
    const float4* src = (const float4*)f + (size_t)row * 256;
    float4 v0 = src[lane], v1 = src[64 + lane], v2 = src[128 + lane], v3 = src[192 + lane];
    float s = v0.x * v0.x + v0.y * v0.y + v0.z * v0.z + v0.w * v0.w
            + v1.x * v1.x + v1.y * v1.y + v1.z * v1.z + v1.w * v1.w
            + v2.x * v2.x + v2.y * v2.y + v2.z * v2.z + v2.w * v2.w
            + v3.x * v3.x + v3.y * v3.y + v3.z * v3.z + v3.w * v3.w;
#pragma unroll
    for (int off = 32; off > 0; off >>= 1) s += __shfl_xor(s, off, 64);
    float zsc = rsqrtf(s) * 32.f;                // z ~ N(0,1)
    unsigned short u0 = pk4(v0, zsc), u1 = pk4(v1, zsc),
                   u2 = pk4(v2, zsc), u3 = pk4(v3, zsc);
    // lane holds elems 256j+4*lane..+3 -> kb_j = 4j + (lane>>4), byte 2*(lane&15)
    unsigned char* tb = fbT + (size_t)(row >> 5) * 16384 + (row & 31) * 32 + (lane & 15) * 2;
    int ko = (lane >> 4) * 1024;
    *(unsigned short*)(tb + ko) = u0;
    *(unsigned short*)(tb + ko + 4096) = u1;
    *(unsigned short*)(tb + ko + 8192) = u2;
    *(unsigned short*)(tb + ko + 12288) = u3;
    if (lane == 0) {
      sL[row] = s * C1F;
      pL[row] = sqrtf(s) * C2F;
    }
  } else {
    int j = b - 2304;                            // W1 column j -> W1t row j
    if (j == 0) {
      if (t < 2) sums[t] = 0.0;
      if (t == 2) *ctr = 0u;                     // completion counter for mlp
    }
    for (int k = t; k < DFEAT; k += 256)
      W1t[(size_t)j * DFEAT + k] = f2bf(W1[(size_t)k * 128 + j]);
  }
}

// ---- kernel 2: Gram via MX-fp4 MFMA, 256x256 LDS-staged tiles ----
// 8 waves/block; wave w computes rows (w&1)*128 (4 slabs) x cols (w>>1)*64 (2
// slabs). K split into 4 phases of K=256; per phase each wave stages 8 KB
// (its A-slab quarter + its B-slab quarter), double-buffered across phases
// with counted s_waitcnt vmcnt(8) so the NEXT phase's loads stay in flight
// under this phase's 32 MFMA + 24 ds_reads. 8 barriers/block (was 32).
__global__ __launch_bounds__(512, 2) void gram_sim(const unsigned char* __restrict__ fbT,
                                                   const float* __restrict__ sL,
                                                   const float* __restrict__ pL,
                                                   double* __restrict__ sums) {
  __shared__ __align__(16) unsigned char stg[2][65536];  // [buf][A 32KB | B 32KB]
  __shared__ float sA[256], pA[256], sB[256], pB[256];
  __shared__ float wpart[8];

  int bid = blockIdx.x, t = threadIdx.x, lane = t & 63, wave = t >> 6;
  // bijective XCD swizzle (666 = 8*83 + 2): consecutive L share an XCD chunk
  int xcd = bid & 7, t8 = bid >> 3;
  int L = (xcd < 2 ? xcd * 84 : 168 + (xcd - 2) * 83) + t8;
  // decode triangular, bcol-major (B-panel L2-hot): panel bcol has bcol+1 rows
  int rem = L, bcol = 0;
  while (rem > bcol) { rem -= (bcol + 1); bcol++; }
  int brow = rem;                                 // brow <= bcol

  if (t < 256) { sA[t] = sL[brow * 256 + t]; pA[t] = pL[brow * 256 + t]; }
  else { int u = t & 255; sB[u] = sL[bcol * 256 + u]; pB[u] = pL[bcol * 256 + u]; }
  __syncthreads();                                // drain before raw barriers

  // staging: wave w copies A-slab w and B-slab w (quarter per phase)
  const unsigned char* srcA = fbT + (size_t)(brow * 8 + wave) * 16384 + lane * 16;
  const unsigned char* srcB = fbT + (size_t)(bcol * 8 + wave) * 16384 + lane * 16;
  char* dstA = (char*)stg + wave * 4096 + lane * 16;
  char* dstB = (char*)stg + 32768 + wave * 4096 + lane * 16;

  // phase q sources bytes [q*4096, q*4096+4096) of each slab (kb = 4q..4q+3)
#define STAGE(buf, q)                                                     \
  {                                                                       \
    const int go = (q) * 4096, lo = (buf) * 65536;                        \
    async_copy16(srcA + go,        dstA + lo);                            \
    async_copy16(srcA + go + 1024, dstA + lo + 1024);                     \
    async_copy16(srcA + go + 2048, dstA + lo + 2048);                     \
    async_copy16(srcA + go + 3072, dstA + lo + 3072);                     \
    async_copy16(srcB + go,        dstB + lo);                            \
    async_copy16(srcB + go + 1024, dstB + lo + 1024);                     \
    async_copy16(srcB + go + 2048, dstB + lo + 2048);                     \
    async_copy16(srcB + go + 3072, dstB + lo + 3072);                     \
  }

  const int r32 = lane & 31, kh = lane >> 5;
  const int loff = r32 * 32 + kh * 16;
  const int wr = (wave & 1) * 128, wc = (wave >> 1) * 64;
  const char* aBase = (const char*)stg + ((wave & 1) * 4) * 4096 + loff;
  const char* bBase = (const char*)stg + 32768 + ((wave >> 1) * 2) * 4096 + loff;

  floatx16 acc[4][2];
#pragma unroll
  for (int mi = 0; mi < 4; mi++)
#pragma unroll
    for (int ni = 0; ni < 2; ni++)
#pragma unroll
      for (int e = 0; e < 16; e++) acc[mi][ni][e] = 0.f;

  // fp4 operands use only the low 4 regs of the i32x8; zero high half ONCE
  union u8x { intx8 v8; intx4 q[2]; };
  u8x A8[4], B8[2];
#pragma unroll
  for (int mi = 0; mi < 4; mi++) A8[mi].q[1] = (intx4){0, 0, 0, 0};
#pragma unroll
  for (int ni = 0; ni < 2; ni++) B8[ni].q[1] = (intx4){0, 0, 0, 0};

  STAGE(0, 0)
  STAGE(1, 1)                                     // 16 loads outstanding / wave
#pragma unroll
  for (int q = 0; q < 4; q++) {
    if (q < 3) asm volatile("s_waitcnt vmcnt(8)" ::: "memory");
    else       asm volatile("s_waitcnt vmcnt(0)" ::: "memory");
    __builtin_amdgcn_s_barrier();                 // phase-q data visible to all
    __builtin_amdgcn_sched_barrier(0);
    const int cur = (q & 1) * 65536;
#pragma unroll
    for (int c = 0; c < 4; c++) {                 // kb = 4q + c
      const int co = cur + c * 1024;
#pragma unroll
      for (int mi = 0; mi < 4; mi++)
        A8[mi].q[0] = *(const intx4*)(aBase + co + mi * 4096);
#pragma unroll
      for (int ni = 0; ni < 2; ni++)
        B8[ni].q[0] = *(const intx4*)(bBase + co + ni * 4096);
#pragma unroll
      for (int mi = 0; mi < 4; mi++)
#pragma unroll
        for (int ni = 0; ni < 2; ni++)
          acc[mi][ni] = __builtin_amdgcn_mfma_scale_f32_32x32x64_f8f6f4(
              A8[mi].v8, B8[ni].v8, acc[mi][ni], 4, 4,   // FMT fp4 / fp4
              0, 0x7F7F7F7F, 0, 0x7F7F7F7F);             // scales = 1.0
    }
    __builtin_amdgcn_sched_barrier(0);
    __builtin_amdgcn_s_barrier();                 // all reads of buf done
    __builtin_amdgcn_sched_barrier(0);
    if (q < 2) STAGE((q & 1), q + 2)
  }
#undef STAGE

  // epilogue: g ~= 1024*cos. C/D layout col=lane&31, row=(reg&3)+8*(reg>>2)+4*kh
  const bool diag = (brow == bcol);
  float lsum = 0.f;
#pragma unroll
  for (int ni = 0; ni < 2; ni++) {
    int j_loc = wc + ni * 32 + r32;
    float sj = sB[j_loc], pj = pB[j_loc];
#pragma unroll
    for (int mi = 0; mi < 4; mi++) {
      int rbase = wr + mi * 32 + 4 * kh;
#pragma unroll
      for (int reg = 0; reg < 16; reg++) {
        int i_loc = rbase + (reg & 3) + 8 * (reg >> 2);
        float g = acc[mi][ni][reg];
        float si = sA[i_loc], pi = pA[i_loc];
        float r = __builtin_amdgcn_rcpf(1024.f + g);
        float del = pi * pj;
        float gam = si + sj + del;
        float sim = __builtin_amdgcn_exp2f(fmaf(-1024.f, gam * r, del));
        if (!diag) {
          lsum += sim;
        } else {
          lsum += (i_loc < j_loc) ? 2.f * sim : (i_loc == j_loc ? 1.f : 0.f);
        }
      }
    }
  }
  if (!diag) lsum *= 2.f;                         // brow<bcol: all i<j, count x2
#pragma unroll
  for (int off = 32; off > 0; off >>= 1) lsum += __shfl_down(lsum, off, 64);
  if (lane == 0) wpart[wave] = lsum;
  __syncthreads();
  if (t == 0) {
    float bs = 0.f;
#pragma unroll
    for (int w = 0; w < 8; w++) bs += wpart[w];
    atomicAdd(&sums[0], (double)bs);
  }
}

// ---- kernel 3: full MLP, 32 rows/block (288 blocks); folds finalize ----
__global__ __launch_bounds__(256) void mlp_full(const float* __restrict__ f,
                                                const unsigned short* __restrict__ W1t,
                                                const float* __restrict__ scores,
                                                const float* __restrict__ W1,
                                                const float* __restrict__ b1,
                                                const float* __restrict__ g1,
                                                const float* __restrict__ be1,
                                                const float* __restrict__ W2, const float* __restrict__ b2,
                                                const float* __restrict__ g2, const float* __restrict__ be2,
                                                const float* __restrict__ W3, const float* __restrict__ b3,
                                                double* __restrict__ sums,
                                                unsigned* __restrict__ ctr,
                                                float* __restrict__ out) {
  int r0 = blockIdx.x * 32;

  __shared__ __align__(16) float As32[32 * 64];         // 8 KB, 16-slot XOR swizzle
  __shared__ __align__(16) unsigned short Bs[128 * 64]; // 16 KB, 8-slot XOR swizzle
  __shared__ float h1s[32][128];                        // 16 KB
  __shared__ float h2s[32][65];                         // 8.3 KB
  __shared__ float sc[32], b1s[128], g1s[128], be1s[128], wls[128], ls[32];

  int t = threadIdx.x, lane = t & 63, wave = t >> 6;
  if (t < 32) sc[t] = scores[r0 + t];
  if (t < 128) {
    b1s[t] = b1[t]; g1s[t] = g1[t]; be1s[t] = be1[t];
    wls[t] = W1[(size_t)DFEAT * 128 + t];
  }

  floatx4 acc[4];
#pragma unroll
  for (int b = 0; b < 4; b++) acc[b] = (floatx4){0.f, 0.f, 0.f, 0.f};

  const int wr = (wave & 1) * 16, wc = (wave >> 1) * 64;

  for (int k0 = 0; k0 < DFEAT; k0 += 64) {
    __syncthreads();
    {
      // A: 512 chunks (32 rows x 16/row); phys p of row r holds logical p^(r&15)
      int c = t, rA = c >> 4, p = c & 15, l = p ^ (rA & 15);
      async_copy16(f + (size_t)(r0 + rA) * DFEAT + k0 + l * 4, (char*)As32 + c * 16);
      c = t + 256; rA = c >> 4; p = c & 15; l = p ^ (rA & 15);
      async_copy16(f + (size_t)(r0 + rA) * DFEAT + k0 + l * 4, (char*)As32 + c * 16);
      // B: 1024 chunks (128 rows x 8/row); phys p holds logical p^(r&7)
#pragma unroll
      for (int q = 0; q < 4; q++) {
        int cc = t + q * 256, rB = cc >> 3, pp = cc & 7, ll = pp ^ (rB & 7);
        async_copy16(W1t + (size_t)rB * DFEAT + k0 + ll * 8, (char*)Bs + cc * 16);
      }
    }
    __syncthreads();

    const int mrow = lane & 15;
#pragma unroll
    for (int ks = 0; ks < 2; ks++) {
      const int kq = ks * 32 + (lane >> 4) * 8;
      short8 a, b[4];
      {
        int row = wr + mrow;
        int l0 = kq >> 2;
        int p0 = l0 ^ (row & 15), p1 = (l0 + 1) ^ (row & 15);
        float4 f0 = *(const float4*)&As32[row * 64 + p0 * 4];
        float4 f1 = *(const float4*)&As32[row * 64 + p1 * 4];
        a[0] = (short)f2bf(f0.x); a[1] = (short)f2bf(f0.y);
        a[2] = (short)f2bf(f0.z); a[3] = (short)f2bf(f0.w);
        a[4] = (short)f2bf(f1.x); a[5] = (short)f2bf(f1.y);
        a[6] = (short)f2bf(f1.z); a[7] = (short)f2bf(f1.w);
      }
#pragma unroll
      for (int nt = 0; nt < 4; nt++) {
        int row = wc + nt * 16 + mrow;
        int p = (kq >> 3) ^ (row & 7);
        b[nt] = *(const short8*)&Bs[row * 64 + p * 8];
      }
#pragma unroll
      for (int nt = 0; nt < 4; nt++)
        acc[nt] = __builtin_amdgcn_mfma_f32_16x16x32_bf16(a, b[nt], acc[nt], 0, 0, 0);
    }
  }

  const float inv = 1.0f / sqrtf(1.0f + 1e-5f);
  const int rq = (lane >> 4) * 4, cn = lane & 15;
#pragma unroll
  for (int nt = 0; nt < 4; nt++) {
    int j = wc + nt * 16 + cn;
    float bj = b1s[j], gj = g1s[j] * inv, bej = be1s[j], wj = wls[j];
#pragma unroll
    for (int rr = 0; rr < 4; rr++) {
      int iL = wr + rq + rr;
      float pre = acc[nt][rr] + sc[iL] * wj + bj;
      h1s[iL][j] = fmaxf(gj * pre + bej, 0.f);
    }
  }
  __syncthreads();

  // layer 2: 128 -> 64. j = t&63, 8 rows/thread (broadcast LDS reads)
  {
    int j = t & 63, rg = (t >> 6) * 8;
    float a2[8];
#pragma unroll
    for (int rr = 0; rr < 8; rr++) a2[rr] = 0.f;
    for (int k = 0; k < 128; k++) {
      float w = W2[k * 64 + j];
#pragma unroll
      for (int rr = 0; rr < 8; rr++) a2[rr] = fmaf(h1s[rg + rr][k], w, a2[rr]);
    }
    float scv = g2[j] * inv, bi = b2[j], be = be2[j];
#pragma unroll
    for (int rr = 0; rr < 8; rr++)
      h2s[rg + rr][j] = fmaxf(scv * (a2[rr] + bi) + be, 0.f);
  }
  __syncthreads();

  // layer 3: 64 -> 1 + sigmoid
  if (t < 32) {
    float z = b3[0];
#pragma unroll
    for (int k = 0; k < 64; k++) z = fmaf(h2s[t][k], W3[k], z);
    ls[t] = 1.f / (1.f + __expf(-z));
  }
  __syncthreads();
  if (t == 0) {
    float s = 0.f;
#pragma unroll
    for (int iL = 0; iL < 32; iL++) s += ls[iL];
    atomicAdd(&sums[1], (double)s);
    // folded finalize: gram ran earlier in-stream, so sums[0] is complete;
    // last mlp block to arrive combines.
    __threadfence();
    unsigned prev = atomicAdd(ctr, 1u);
    if (prev == 287u) {
      __threadfence();
      double s0 = ((volatile double*)sums)[0];
      double s1 = ((volatile double*)sums)[1];
      out[0] = (float)((s1 / (double)N_IMG) * (s0 / ((double)N_IMG * (double)N_IMG)));
    }
  }
}

extern "C" void kernel_launch(void* const* d_in, const int* in_sizes, int n_in,
                              void* d_out, int out_size, void* d_ws, size_t ws_size,
                              hipStream_t stream) {
  const float* f      = (const float*)d_in[0];
  const float* scores = (const float*)d_in[1];
  const float* W1 = (const float*)d_in[2];
  const float* b1 = (const float*)d_in[3];
  const float* g1 = (const float*)d_in[4];
  const float* be1 = (const float*)d_in[5];
  const float* W2 = (const float*)d_in[6];
  const float* b2 = (const float*)d_in[7];
  const float* g2 = (const float*)d_in[8];
  const float* be2 = (const float*)d_in[9];
  const float* W3 = (const float*)d_in[10];
  const float* b3 = (const float*)d_in[11];

  // workspace layout (~5.06 MB total)
  char* ws = (char*)d_ws;
  unsigned char* fbT  = (unsigned char*)ws;                  // 4,718,592 B (fp4 tiled)
  float* sL           = (float*)(ws + 4718592);              // 36,864 B  (s * C1)
  float* pL           = (float*)(ws + 4755456);              // 36,864 B  (sqrt(s) * C2)
  unsigned short* W1t = (unsigned short*)(ws + 4792320);     // 262,144 B
  double* sums        = (double*)(ws + 5054464);             // 16 B
  unsigned* ctr       = (unsigned*)(ws + 5054480);           // 4 B (completion)

  convert_prep<<<2432, 256, 0, stream>>>(f, W1, fbT, sL, pL, W1t, sums, ctr);
  gram_sim<<<NPAIR2, 512, 0, stream>>>(fbT, sL, pL, sums);
  mlp_full<<<288, 256, 0, stream>>>(f, W1t, scores, W1, b1, g1, be1,
                                    W2, b2, g2, be2, W3, b3, sums, ctr,
                                    (float*)d_out);
}